// Round 1
// baseline (5214.832 us; speedup 1.0000x reference)
//
#include <hip/hip_runtime.h>

#define T_TOK 4096
#define SEQ   2048
#define HID   1024
#define NH    16
#define HD    64
#define INTER 4096
#define NLAYER 8
#define VOCAB 32000

typedef short short8 __attribute__((ext_vector_type(8)));
typedef float f32x4  __attribute__((ext_vector_type(4)));

__device__ __forceinline__ unsigned short f2bf(float f){
  unsigned int u = __builtin_bit_cast(unsigned int, f);
  u += 0x7fffu + ((u >> 16) & 1u);
  return (unsigned short)(u >> 16);
}
__device__ __forceinline__ float bf2f(unsigned short b){
  unsigned int u = ((unsigned int)b) << 16;
  return __builtin_bit_cast(float, u);
}

// ---------------- embedding gather ----------------
__global__ __launch_bounds__(256) void embed_kernel(const int* __restrict__ ids,
                                                    const float* __restrict__ W,
                                                    float* __restrict__ h){
  int i = blockIdx.x * 256 + threadIdx.x;   // float4 index over [T][256]
  int t = i >> 8, c = i & 255;
  ((float4*)h)[i] = ((const float4*)(W + (size_t)ids[t] * HID))[c];
}

// ---------------- rope tables ----------------
__global__ __launch_bounds__(256) void rope_tab_kernel(float* __restrict__ cosT,
                                                       float* __restrict__ sinT){
  int i = blockIdx.x * 256 + threadIdx.x;   // s*32 + f
  int s = i >> 5, f = i & 31;
  float inv = expf(-((2.0f * (float)f) / 64.0f) * logf(100000.0f));
  float ang = (float)s * inv;
  cosT[i] = cosf(ang);
  sinT[i] = sinf(ang);
}

// ---------------- rmsnorm (fp32 in -> bf16 out, optional fp32 normed copy) ----------------
__global__ __launch_bounds__(256) void rmsnorm_kernel(const float* __restrict__ h,
                                                      const float* __restrict__ w,
                                                      unsigned short* __restrict__ out,
                                                      float* hcopy){
  int t = blockIdx.x, tid = threadIdx.x;
  float4 v = ((const float4*)(h + (size_t)t * HID))[tid];
  float ss = v.x*v.x + v.y*v.y + v.z*v.z + v.w*v.w;
  #pragma unroll
  for (int m = 1; m < 64; m <<= 1) ss += __shfl_xor(ss, m);
  __shared__ float red[4];
  if ((tid & 63) == 0) red[tid >> 6] = ss;
  __syncthreads();
  float r = rsqrtf((red[0] + red[1] + red[2] + red[3]) * (1.0f / HID) + 1e-5f);
  float4 wv = ((const float4*)w)[tid];
  float nx = v.x * r * wv.x;
  float ny = v.y * r * wv.y;
  float nz = v.z * r * wv.z;
  float nw = v.w * r * wv.w;
  ushort4 o;
  o.x = f2bf(nx); o.y = f2bf(ny); o.z = f2bf(nz); o.w = f2bf(nw);
  ((ushort4*)(out + (size_t)t * HID))[tid] = o;
  if (hcopy){
    float4 hv; hv.x = nx; hv.y = ny; hv.z = nz; hv.w = nw;
    ((float4*)(hcopy + (size_t)t * HID))[tid] = hv;
  }
}

// ---------------- rope apply (in-place on bf16 q,k) ----------------
__global__ __launch_bounds__(256) void rope_kernel(unsigned short* __restrict__ q,
                                                   unsigned short* __restrict__ k,
                                                   const float* __restrict__ cosT,
                                                   const float* __restrict__ sinT){
  int i = blockIdx.x * 256 + threadIdx.x;   // t*512 + hh*32 + f
  int t = i >> 9, rem = i & 511;
  int hh = rem >> 5, f = rem & 31;
  int s = t & (SEQ - 1);
  float c = cosT[s * 32 + f], sn = sinT[s * 32 + f];
  size_t base = (size_t)t * HID + hh * HD + f;
  float q0 = bf2f(q[base]), q1 = bf2f(q[base + 32]);
  q[base]      = f2bf(q0 * c - q1 * sn);
  q[base + 32] = f2bf(q1 * c + q0 * sn);
  float k0 = bf2f(k[base]), k1 = bf2f(k[base + 32]);
  k[base]      = f2bf(k0 * c - k1 * sn);
  k[base + 32] = f2bf(k1 * c + k0 * sn);
}

// ---------------- GEMM: C[M][N] = A_bf16[M][K] x B_f32[K][N] ----------------
// MODE 0: bf16 out. MODE 1: f32 out = resid + acc (in-place residual).
// MODE 2: bf16 transposed out (C^T at [col][row], stride ldt). MODE 3: f32 out.
template<int MODE>
__global__ __launch_bounds__(256, 2) void gemm_kernel(const unsigned short* __restrict__ A,
                                                      const float* __restrict__ Bw,
                                                      void* Cout, const float* resid,
                                                      int M, int N, int K, int ldt){
  __shared__ unsigned short As[128 * 32];   // [row][k]
  __shared__ unsigned short Bs[128 * 32];   // [col][k], chunk-swizzled
  const int tid = threadIdx.x;
  const int lane = tid & 63, wid = tid >> 6;
  const int l15 = lane & 15, g = lane >> 4;
  const int wr = wid >> 1, wc = wid & 1;
  const int m0 = blockIdx.x * 128, n0 = blockIdx.y * 128;
  const int bcol = tid & 127, bhalf = tid >> 7;

  f32x4 acc[4][4];
  #pragma unroll
  for (int m = 0; m < 4; ++m)
    #pragma unroll
    for (int n = 0; n < 4; ++n)
      #pragma unroll
      for (int i = 0; i < 4; ++i) acc[m][n][i] = 0.0f;

  for (int kk = 0; kk < K; kk += 32){
    __syncthreads();
    // stage A (bf16): 128x32, 16B per thread x2
    #pragma unroll
    for (int cc = 0; cc < 2; ++cc){
      int c = tid + cc * 256;
      int row = c >> 2, kc = (c & 3) << 3;
      uint4 d = *(const uint4*)(A + (size_t)(m0 + row) * K + kk + kc);
      *(uint4*)(&As[row * 32 + kc]) = d;
    }
    // stage B (f32 -> bf16), transposed to [col][k], chunk-XOR swizzle
    {
      const float* bp = Bw + (size_t)(kk + bhalf * 16) * N + n0 + bcol;
      float f[16];
      #pragma unroll
      for (int j = 0; j < 16; ++j) f[j] = bp[(size_t)j * N];
      unsigned int pk[8];
      #pragma unroll
      for (int j = 0; j < 8; ++j)
        pk[j] = (unsigned int)f2bf(f[2*j]) | ((unsigned int)f2bf(f[2*j+1]) << 16);
      int sw = (bcol >> 1) & 3;
      int c0 = ((bhalf << 1)     ) ^ sw;
      int c1 = ((bhalf << 1) | 1 ) ^ sw;
      uint4 w0; w0.x = pk[0]; w0.y = pk[1]; w0.z = pk[2]; w0.w = pk[3];
      uint4 w1; w1.x = pk[4]; w1.y = pk[5]; w1.z = pk[6]; w1.w = pk[7];
      *(uint4*)(&Bs[bcol * 32 + c0 * 8]) = w0;
      *(uint4*)(&Bs[bcol * 32 + c1 * 8]) = w1;
    }
    __syncthreads();
    short8 a[4], b[4];
    #pragma unroll
    for (int m = 0; m < 4; ++m)
      a[m] = *(const short8*)(&As[(wr*64 + m*16 + l15) * 32 + g*8]);
    #pragma unroll
    for (int n = 0; n < 4; ++n){
      int col = wc*64 + n*16 + l15;
      b[n] = *(const short8*)(&Bs[col * 32 + (g ^ ((col >> 1) & 3)) * 8]);
    }
    #pragma unroll
    for (int m = 0; m < 4; ++m)
      #pragma unroll
      for (int n = 0; n < 4; ++n)
        acc[m][n] = __builtin_amdgcn_mfma_f32_16x16x32_bf16(a[m], b[n], acc[m][n], 0, 0, 0);
  }
  // epilogue. C layout: col = lane&15, row = (lane>>4)*4 + i
  #pragma unroll
  for (int m = 0; m < 4; ++m){
    #pragma unroll
    for (int n = 0; n < 4; ++n){
      int row0 = m0 + wr*64 + m*16 + g*4;
      int col  = n0 + wc*64 + n*16 + l15;
      #pragma unroll
      for (int i = 0; i < 4; ++i){
        float v = acc[m][n][i];
        if (MODE == 0){
          ((unsigned short*)Cout)[(size_t)(row0 + i) * N + col] = f2bf(v);
        } else if (MODE == 1){
          size_t idx = (size_t)(row0 + i) * N + col;
          ((float*)Cout)[idx] = resid[idx] + v;
        } else if (MODE == 2){
          ((unsigned short*)Cout)[(size_t)col * ldt + (row0 + i)] = f2bf(v);
        } else {
          ((float*)Cout)[(size_t)(row0 + i) * N + col] = v;
        }
      }
    }
  }
}

// ---------------- flash attention: 1 wave = 32 q rows ----------------
__global__ __launch_bounds__(64) void attn_kernel(const unsigned short* __restrict__ q,
                                                  const unsigned short* __restrict__ k,
                                                  const unsigned short* __restrict__ vt,
                                                  unsigned short* __restrict__ ctx){
  const int lane = threadIdx.x;
  const int l15 = lane & 15, g = lane >> 4;
  const int q0 = blockIdx.x * 32;
  const int hh = blockIdx.y;
  const int b  = blockIdx.z;
  const int tb = b * SEQ;

  __shared__ unsigned short p_lds[2][16][72];  // padded: stride 144B (16B-aligned)

  short8 qa[2][2];
  #pragma unroll
  for (int qs = 0; qs < 2; ++qs)
    #pragma unroll
    for (int kd = 0; kd < 2; ++kd)
      qa[qs][kd] = *(const short8*)(q + (size_t)(tb + q0 + qs*16 + l15) * HID + hh*HD + kd*32 + g*8);

  float m_run[2][4], l_run[2][4];
  f32x4 o_acc[2][4];
  #pragma unroll
  for (int qs = 0; qs < 2; ++qs)
    #pragma unroll
    for (int i = 0; i < 4; ++i){ m_run[qs][i] = -1e30f; l_run[qs][i] = 0.0f; }
  #pragma unroll
  for (int qs = 0; qs < 2; ++qs)
    #pragma unroll
    for (int dt = 0; dt < 4; ++dt)
      #pragma unroll
      for (int i = 0; i < 4; ++i) o_acc[qs][dt][i] = 0.0f;

  const int ntile = ((q0 + 31) >> 6) + 1;
  for (int kt = 0; kt < ntile; ++kt){
    const int kv0 = kt * 64;
    short8 kb[4][2];
    #pragma unroll
    for (int ct = 0; ct < 4; ++ct)
      #pragma unroll
      for (int kd = 0; kd < 2; ++kd)
        kb[ct][kd] = *(const short8*)(k + (size_t)(tb + kv0 + ct*16 + l15) * HID + hh*HD + kd*32 + g*8);

    #pragma unroll
    for (int qs = 0; qs < 2; ++qs){
      float pv[4][4];
      #pragma unroll
      for (int ct = 0; ct < 4; ++ct){
        f32x4 sc;
        #pragma unroll
        for (int i = 0; i < 4; ++i) sc[i] = 0.0f;
        sc = __builtin_amdgcn_mfma_f32_16x16x32_bf16(qa[qs][0], kb[ct][0], sc, 0, 0, 0);
        sc = __builtin_amdgcn_mfma_f32_16x16x32_bf16(qa[qs][1], kb[ct][1], sc, 0, 0, 0);
        #pragma unroll
        for (int i = 0; i < 4; ++i){
          float s = sc[i] * 0.125f;
          s = fminf(fmaxf(s, -1000.0f), 1000.0f);
          int row = q0 + qs*16 + g*4 + i;
          int col = kv0 + ct*16 + l15;
          pv[ct][i] = (col > row) ? -1e30f : s;
        }
      }
      #pragma unroll
      for (int i = 0; i < 4; ++i){
        float mx = fmaxf(fmaxf(pv[0][i], pv[1][i]), fmaxf(pv[2][i], pv[3][i]));
        #pragma unroll
        for (int msk = 1; msk < 16; msk <<= 1) mx = fmaxf(mx, __shfl_xor(mx, msk));
        float mnew = fmaxf(m_run[qs][i], mx);
        float scale = __expf(m_run[qs][i] - mnew);
        float psum = 0.0f;
        #pragma unroll
        for (int ct = 0; ct < 4; ++ct){
          float p = __expf(pv[ct][i] - mnew);
          pv[ct][i] = p; psum += p;
        }
        #pragma unroll
        for (int msk = 1; msk < 16; msk <<= 1) psum += __shfl_xor(psum, msk);
        l_run[qs][i] = l_run[qs][i] * scale + psum;
        m_run[qs][i] = mnew;
        #pragma unroll
        for (int dt = 0; dt < 4; ++dt) o_acc[qs][dt][i] *= scale;
      }
      #pragma unroll
      for (int ct = 0; ct < 4; ++ct)
        #pragma unroll
        for (int i = 0; i < 4; ++i)
          p_lds[qs][g*4 + i][ct*16 + l15] = f2bf(pv[ct][i]);
    }
    __syncthreads();
    #pragma unroll
    for (int ks = 0; ks < 2; ++ks){
      short8 vb[4];
      #pragma unroll
      for (int dt = 0; dt < 4; ++dt)
        vb[dt] = *(const short8*)(vt + (size_t)(hh*HD + dt*16 + l15) * T_TOK + tb + kv0 + ks*32 + g*8);
      #pragma unroll
      for (int qs = 0; qs < 2; ++qs){
        short8 ap = *(const short8*)(&p_lds[qs][l15][ks*32 + g*8]);
        #pragma unroll
        for (int dt = 0; dt < 4; ++dt)
          o_acc[qs][dt] = __builtin_amdgcn_mfma_f32_16x16x32_bf16(ap, vb[dt], o_acc[qs][dt], 0, 0, 0);
      }
    }
    __syncthreads();
  }
  #pragma unroll
  for (int qs = 0; qs < 2; ++qs)
    #pragma unroll
    for (int dt = 0; dt < 4; ++dt)
      #pragma unroll
      for (int i = 0; i < 4; ++i){
        float o = o_acc[qs][dt][i] / l_run[qs][i];
        ctx[(size_t)(tb + q0 + qs*16 + g*4 + i) * HID + hh*HD + dt*16 + l15] = f2bf(o);
      }
}

// ---------------- silu(g)*u -> g (bf16) ----------------
__global__ __launch_bounds__(256) void silu_mul_kernel(unsigned short* __restrict__ gbuf,
                                                       const unsigned short* __restrict__ ubuf){
  int i = blockIdx.x * 256 + threadIdx.x;
  ushort4 gv = ((const ushort4*)gbuf)[i];
  ushort4 uv = ((const ushort4*)ubuf)[i];
  ushort4 o;
  float x;
  x = bf2f(gv.x); o.x = f2bf((x / (1.0f + __expf(-x))) * bf2f(uv.x));
  x = bf2f(gv.y); o.y = f2bf((x / (1.0f + __expf(-x))) * bf2f(uv.y));
  x = bf2f(gv.z); o.z = f2bf((x / (1.0f + __expf(-x))) * bf2f(uv.z));
  x = bf2f(gv.w); o.w = f2bf((x / (1.0f + __expf(-x))) * bf2f(uv.w));
  ((ushort4*)gbuf)[i] = o;
}

extern "C" void kernel_launch(void* const* d_in, const int* in_sizes, int n_in,
                              void* d_out, int out_size, void* d_ws, size_t ws_size,
                              hipStream_t stream){
  const int*   ids    = (const int*)d_in[0];
  const float* embedW = (const float*)d_in[1];
  const float* Wq = (const float*)d_in[2];
  const float* Wk = (const float*)d_in[3];
  const float* Wv = (const float*)d_in[4];
  const float* Wo = (const float*)d_in[5];
  const float* Wg = (const float*)d_in[6];
  const float* Wu = (const float*)d_in[7];
  const float* Wd = (const float*)d_in[8];
  const float* n1 = (const float*)d_in[9];
  const float* n2 = (const float*)d_in[10];
  const float* nf = (const float*)d_in[11];
  const float* Wh = (const float*)d_in[12];
  float* out = (float*)d_out;

  // scratch inside d_out's logits region (dead until the final head GEMM,
  // which reads only xn from ws)
  char* sc = (char*)d_out;
  unsigned short* qb  = (unsigned short*)(sc + 0);
  unsigned short* kb  = (unsigned short*)(sc + 8388608);
  unsigned short* vt  = (unsigned short*)(sc + 16777216);   // V^T [HID][T]
  unsigned short* ctx = (unsigned short*)(sc + 25165824);
  unsigned short* gb  = (unsigned short*)(sc + 33554432);
  unsigned short* ub  = (unsigned short*)(sc + 67108864);
  float* cosT = (float*)(sc + 100663296);
  float* sinT = (float*)(sc + 100925440);

  unsigned short* xn = (unsigned short*)d_ws;               // 8 MB bf16
  float* h;
  if (ws_size >= 25165824u){
    h = (float*)((char*)d_ws + 8388608);                    // 16 MB fp32
  } else {
    h = (float*)(sc + 201326592);                           // fallback in d_out scratch
  }

  embed_kernel<<<4096, 256, 0, stream>>>(ids, embedW, h);
  rope_tab_kernel<<<256, 256, 0, stream>>>(cosT, sinT);

  for (int l = 0; l < NLAYER; ++l){
    const float* wq = Wq + (size_t)l * HID * HID;
    const float* wk = Wk + (size_t)l * HID * HID;
    const float* wv = Wv + (size_t)l * HID * HID;
    const float* wo = Wo + (size_t)l * HID * HID;
    const float* wg = Wg + (size_t)l * HID * INTER;
    const float* wu = Wu + (size_t)l * HID * INTER;
    const float* wd = Wd + (size_t)l * INTER * HID;

    rmsnorm_kernel<<<4096, 256, 0, stream>>>(h, n1 + l*HID, xn, nullptr);
    gemm_kernel<0><<<dim3(32, 8),  256, 0, stream>>>(xn, wq, qb, nullptr, T_TOK, HID, HID, 0);
    gemm_kernel<0><<<dim3(32, 8),  256, 0, stream>>>(xn, wk, kb, nullptr, T_TOK, HID, HID, 0);
    gemm_kernel<2><<<dim3(32, 8),  256, 0, stream>>>(xn, wv, vt, nullptr, T_TOK, HID, HID, T_TOK);
    rope_kernel<<<8192, 256, 0, stream>>>(qb, kb, cosT, sinT);
    attn_kernel<<<dim3(64, 16, 2), 64, 0, stream>>>(qb, kb, vt, ctx);
    gemm_kernel<1><<<dim3(32, 8),  256, 0, stream>>>(ctx, wo, h, h, T_TOK, HID, HID, 0);

    rmsnorm_kernel<<<4096, 256, 0, stream>>>(h, n2 + l*HID, xn, nullptr);
    gemm_kernel<0><<<dim3(32, 32), 256, 0, stream>>>(xn, wg, gb, nullptr, T_TOK, INTER, HID, 0);
    gemm_kernel<0><<<dim3(32, 32), 256, 0, stream>>>(xn, wu, ub, nullptr, T_TOK, INTER, HID, 0);
    silu_mul_kernel<<<16384, 256, 0, stream>>>(gb, ub);
    gemm_kernel<1><<<dim3(32, 8),  256, 0, stream>>>(gb, wd, h, h, T_TOK, HID, INTER, 0);
  }

  // final norm: xn (bf16) for head GEMM, fp32 normed h to d_out tail
  rmsnorm_kernel<<<4096, 256, 0, stream>>>(h, nf, xn, out + 131072000);
  gemm_kernel<3><<<dim3(32, 250), 256, 0, stream>>>(xn, Wh, out, nullptr, T_TOK, VOCAB, HID, 0);
}

// Round 2
// 3834.142 us; speedup vs baseline: 1.3601x; 1.3601x over previous
//
#include <hip/hip_runtime.h>

#define T_TOK 4096
#define SEQ   2048
#define HID   1024
#define NH    16
#define HD    64
#define INTER 4096
#define NLAYER 8
#define VOCAB 32000

typedef short short8 __attribute__((ext_vector_type(8)));
typedef float f32x4  __attribute__((ext_vector_type(4)));

__device__ __forceinline__ unsigned short f2bf(float f){
  unsigned int u = __builtin_bit_cast(unsigned int, f);
  u += 0x7fffu + ((u >> 16) & 1u);
  return (unsigned short)(u >> 16);
}
__device__ __forceinline__ float bf2f(unsigned short b){
  unsigned int u = ((unsigned int)b) << 16;
  return __builtin_bit_cast(float, u);
}

#define GLOAD_LDS16(gsrc, ldst) \
  __builtin_amdgcn_global_load_lds((const __attribute__((address_space(1))) void*)(gsrc), \
                                   (__attribute__((address_space(3))) void*)(ldst), 16, 0, 0)

// ---------------- embedding gather ----------------
__global__ __launch_bounds__(256) void embed_kernel(const int* __restrict__ ids,
                                                    const float* __restrict__ W,
                                                    float* __restrict__ h){
  int i = blockIdx.x * 256 + threadIdx.x;   // float4 index over [T][256]
  int t = i >> 8, c = i & 255;
  ((float4*)h)[i] = ((const float4*)(W + (size_t)ids[t] * HID))[c];
}

// ---------------- rope tables ----------------
__global__ __launch_bounds__(256) void rope_tab_kernel(float* __restrict__ cosT,
                                                       float* __restrict__ sinT){
  int i = blockIdx.x * 256 + threadIdx.x;   // s*32 + f
  int s = i >> 5, f = i & 31;
  float inv = expf(-((2.0f * (float)f) / 64.0f) * logf(100000.0f));
  float ang = (float)s * inv;
  cosT[i] = cosf(ang);
  sinT[i] = sinf(ang);
}

// ---------------- rmsnorm (fp32 in -> bf16 out, optional fp32 normed copy) ----------------
__global__ __launch_bounds__(256) void rmsnorm_kernel(const float* __restrict__ h,
                                                      const float* __restrict__ w,
                                                      unsigned short* __restrict__ out,
                                                      float* hcopy){
  int t = blockIdx.x, tid = threadIdx.x;
  float4 v = ((const float4*)(h + (size_t)t * HID))[tid];
  float ss = v.x*v.x + v.y*v.y + v.z*v.z + v.w*v.w;
  #pragma unroll
  for (int m = 1; m < 64; m <<= 1) ss += __shfl_xor(ss, m);
  __shared__ float red[4];
  if ((tid & 63) == 0) red[tid >> 6] = ss;
  __syncthreads();
  float r = rsqrtf((red[0] + red[1] + red[2] + red[3]) * (1.0f / HID) + 1e-5f);
  float4 wv = ((const float4*)w)[tid];
  float nx = v.x * r * wv.x;
  float ny = v.y * r * wv.y;
  float nz = v.z * r * wv.z;
  float nw = v.w * r * wv.w;
  ushort4 o;
  o.x = f2bf(nx); o.y = f2bf(ny); o.z = f2bf(nz); o.w = f2bf(nw);
  ((ushort4*)(out + (size_t)t * HID))[tid] = o;
  if (hcopy){
    float4 hv; hv.x = nx; hv.y = ny; hv.z = nz; hv.w = nw;
    ((float4*)(hcopy + (size_t)t * HID))[tid] = hv;
  }
}

// ---------------- rope apply (in-place on bf16 q,k) ----------------
__global__ __launch_bounds__(256) void rope_kernel(unsigned short* __restrict__ q,
                                                   unsigned short* __restrict__ k,
                                                   const float* __restrict__ cosT,
                                                   const float* __restrict__ sinT){
  int i = blockIdx.x * 256 + threadIdx.x;   // t*512 + hh*32 + f
  int t = i >> 9, rem = i & 511;
  int hh = rem >> 5, f = rem & 31;
  int s = t & (SEQ - 1);
  float c = cosT[s * 32 + f], sn = sinT[s * 32 + f];
  size_t base = (size_t)t * HID + hh * HD + f;
  float q0 = bf2f(q[base]), q1 = bf2f(q[base + 32]);
  q[base]      = f2bf(q0 * c - q1 * sn);
  q[base + 32] = f2bf(q1 * c + q0 * sn);
  float k0 = bf2f(k[base]), k1 = bf2f(k[base + 32]);
  k[base]      = f2bf(k0 * c - k1 * sn);
  k[base + 32] = f2bf(k1 * c + k0 * sn);
}

// ---------------- weight convert: fp32 [K][N] -> bf16 W^T [N][K], chunk-XOR swizzled ----
// element (n,k): kb=k>>6, c=(k>>3)&7, j=k&7 stored at n*K + kb*64 + ((c^(n&7))<<3) + j
__global__ __launch_bounds__(256) void convert_w_kernel(const float* __restrict__ W,
                                                        unsigned short* __restrict__ Wt,
                                                        int K, int N){
  __shared__ unsigned short t_lds[64][72];
  W  += (size_t)blockIdx.z * K * N;
  Wt += (size_t)blockIdx.z * K * N;
  const int n0 = blockIdx.x * 64, k0 = blockIdx.y * 64;
  const int tid = threadIdx.x;
  const int tr = tid >> 4, tc = tid & 15;
  #pragma unroll
  for (int i = 0; i < 4; ++i){
    int kk = tr + i * 16;
    float4 v = *(const float4*)(W + (size_t)(k0 + kk) * N + n0 + tc * 4);
    t_lds[tc*4+0][kk] = f2bf(v.x);
    t_lds[tc*4+1][kk] = f2bf(v.y);
    t_lds[tc*4+2][kk] = f2bf(v.z);
    t_lds[tc*4+3][kk] = f2bf(v.w);
  }
  __syncthreads();
  const int n = tid >> 2, cp = tid & 3;
  #pragma unroll
  for (int j = 0; j < 2; ++j){
    int c = cp * 2 + j;
    uint4 d = *(const uint4*)(&t_lds[n][c * 8]);
    *(uint4*)(Wt + (size_t)(n0 + n) * K + k0 + ((c ^ (n & 7)) << 3)) = d;
  }
}

// ---------------- GEMM core: A bf16 [M][K], Bt bf16 [N][K] pre-swizzled ----------------
// 128x128 tile, BK=64, global_load_lds staging, swizzled ds_read_b128 fragments.
__device__ __forceinline__ void gemm_core(const unsigned short* __restrict__ A,
                                          const unsigned short* __restrict__ Bt,
                                          int K, int m0, int n0,
                                          unsigned short* As, unsigned short* Bs,
                                          f32x4 (&acc)[4][4]){
  const int tid = threadIdx.x;
  const int lane = tid & 63, w = tid >> 6;
  const int l15 = lane & 15, g = lane >> 4;
  const int lr = lane >> 3;          // sub-row 0..7 within 8-row stage block
  const int lc = lane & 7;           // LDS chunk position 0..7
  const int wr = w >> 1, wc = w & 1;
  const int axor = ((lc ^ lr) << 3); // A source chunk (pre-inverse-swizzled)

  #pragma unroll
  for (int m = 0; m < 4; ++m)
    #pragma unroll
    for (int n = 0; n < 4; ++n)
      #pragma unroll
      for (int i = 0; i < 4; ++i) acc[m][n][i] = 0.0f;

  for (int kk = 0; kk < K; kk += 64){
    __syncthreads();
    #pragma unroll
    for (int i = 0; i < 4; ++i){
      int rb = (i * 4 + w) * 8;
      GLOAD_LDS16(A  + (size_t)(m0 + rb + lr) * K + kk + axor,      As + rb * 64);
      GLOAD_LDS16(Bt + (size_t)(n0 + rb + lr) * K + kk + (lc << 3), Bs + rb * 64);
    }
    __syncthreads();
    short8 a[4][2], b[4][2];
    const int x = l15 & 7;
    #pragma unroll
    for (int m = 0; m < 4; ++m){
      int row = wr * 64 + m * 16 + l15;
      a[m][0] = *(const short8*)(As + row * 64 + ((g       ^ x) << 3));
      a[m][1] = *(const short8*)(As + row * 64 + (((4 + g) ^ x) << 3));
    }
    #pragma unroll
    for (int n = 0; n < 4; ++n){
      int row = wc * 64 + n * 16 + l15;
      b[n][0] = *(const short8*)(Bs + row * 64 + ((g       ^ x) << 3));
      b[n][1] = *(const short8*)(Bs + row * 64 + (((4 + g) ^ x) << 3));
    }
    #pragma unroll
    for (int m = 0; m < 4; ++m)
      #pragma unroll
      for (int n = 0; n < 4; ++n){
        acc[m][n] = __builtin_amdgcn_mfma_f32_16x16x32_bf16(a[m][0], b[n][0], acc[m][n], 0, 0, 0);
        acc[m][n] = __builtin_amdgcn_mfma_f32_16x16x32_bf16(a[m][1], b[n][1], acc[m][n], 0, 0, 0);
      }
  }
}

// MODE 0: bf16 out [M][N]. MODE 1: f32 out = resid + acc. MODE 2: bf16 C^T [col][ldt].
// MODE 3: f32 out.
template<int MODE>
__device__ __forceinline__ void gemm_epi(const f32x4 (&acc)[4][4], void* Cout,
                                         const float* __restrict__ resid,
                                         int N, int m0, int n0, int ldt){
  const int tid = threadIdx.x;
  const int lane = tid & 63, w = tid >> 6;
  const int l15 = lane & 15, g = lane >> 4;
  const int wr = w >> 1, wc = w & 1;
  #pragma unroll
  for (int m = 0; m < 4; ++m){
    #pragma unroll
    for (int n = 0; n < 4; ++n){
      int row0 = m0 + wr * 64 + m * 16 + g * 4;
      int col  = n0 + wc * 64 + n * 16 + l15;
      #pragma unroll
      for (int i = 0; i < 4; ++i){
        float v = acc[m][n][i];
        if (MODE == 0){
          ((unsigned short*)Cout)[(size_t)(row0 + i) * N + col] = f2bf(v);
        } else if (MODE == 1){
          size_t idx = (size_t)(row0 + i) * N + col;
          ((float*)Cout)[idx] = resid[idx] + v;
        } else if (MODE == 2){
          ((unsigned short*)Cout)[(size_t)col * ldt + (row0 + i)] = f2bf(v);
        } else {
          ((float*)Cout)[(size_t)(row0 + i) * N + col] = v;
        }
      }
    }
  }
}

template<int MODE>
__global__ __launch_bounds__(256) void gemm_bf16(const unsigned short* __restrict__ A,
                                                 const unsigned short* __restrict__ Bt,
                                                 void* Cout, const float* resid,
                                                 int K, int N, int ldt){
  __shared__ unsigned short As[128 * 64];
  __shared__ unsigned short Bs[128 * 64];
  f32x4 acc[4][4];
  gemm_core(A, Bt, K, blockIdx.x * 128, blockIdx.y * 128, As, Bs, acc);
  gemm_epi<MODE>(acc, Cout, resid, N, blockIdx.x * 128, blockIdx.y * 128, ldt);
}

// fused QKV: grid.y = 24 (8 q | 8 k | 8 v-transposed)
__global__ __launch_bounds__(256) void gemm_qkv(const unsigned short* __restrict__ A,
                                                const unsigned short* __restrict__ BtQ,
                                                const unsigned short* __restrict__ BtK,
                                                const unsigned short* __restrict__ BtV,
                                                unsigned short* qb, unsigned short* kb,
                                                unsigned short* vt){
  __shared__ unsigned short As[128 * 64];
  __shared__ unsigned short Bs[128 * 64];
  const int nb = blockIdx.y, sel = nb >> 3, n0 = (nb & 7) * 128;
  const unsigned short* Bt = (sel == 0) ? BtQ : (sel == 1) ? BtK : BtV;
  f32x4 acc[4][4];
  gemm_core(A, Bt, HID, blockIdx.x * 128, n0, As, Bs, acc);
  if (sel == 0)      gemm_epi<0>(acc, qb, nullptr, HID, blockIdx.x * 128, n0, 0);
  else if (sel == 1) gemm_epi<0>(acc, kb, nullptr, HID, blockIdx.x * 128, n0, 0);
  else               gemm_epi<2>(acc, vt, nullptr, HID, blockIdx.x * 128, n0, T_TOK);
}

// fused gate+up: grid.y = 64 (32 gate | 32 up)
__global__ __launch_bounds__(256) void gemm_gu(const unsigned short* __restrict__ A,
                                               const unsigned short* __restrict__ BtG,
                                               const unsigned short* __restrict__ BtU,
                                               unsigned short* gb, unsigned short* ub){
  __shared__ unsigned short As[128 * 64];
  __shared__ unsigned short Bs[128 * 64];
  const int nb = blockIdx.y, sel = nb >> 5, n0 = (nb & 31) * 128;
  f32x4 acc[4][4];
  gemm_core(A, sel ? BtU : BtG, HID, blockIdx.x * 128, n0, As, Bs, acc);
  gemm_epi<0>(acc, sel ? ub : gb, nullptr, INTER, blockIdx.x * 128, n0, 0);
}

// ---------------- fallback GEMM with fp32 B (head only) ----------------
__global__ __launch_bounds__(256, 2) void gemm_f32b(const unsigned short* __restrict__ A,
                                                    const float* __restrict__ Bw,
                                                    float* __restrict__ Cout,
                                                    int M, int N, int K){
  __shared__ unsigned short As[128 * 32];
  __shared__ unsigned short Bs[128 * 32];
  const int tid = threadIdx.x;
  const int lane = tid & 63, wid = tid >> 6;
  const int l15 = lane & 15, g = lane >> 4;
  const int wr = wid >> 1, wc = wid & 1;
  const int m0 = blockIdx.x * 128, n0 = blockIdx.y * 128;
  const int bcol = tid & 127, bhalf = tid >> 7;
  f32x4 acc[4][4];
  #pragma unroll
  for (int m = 0; m < 4; ++m)
    #pragma unroll
    for (int n = 0; n < 4; ++n)
      #pragma unroll
      for (int i = 0; i < 4; ++i) acc[m][n][i] = 0.0f;
  for (int kk = 0; kk < K; kk += 32){
    __syncthreads();
    #pragma unroll
    for (int cc = 0; cc < 2; ++cc){
      int c = tid + cc * 256;
      int row = c >> 2, kc = (c & 3) << 3;
      uint4 d = *(const uint4*)(A + (size_t)(m0 + row) * K + kk + kc);
      *(uint4*)(&As[row * 32 + kc]) = d;
    }
    {
      const float* bp = Bw + (size_t)(kk + bhalf * 16) * N + n0 + bcol;
      float f[16];
      #pragma unroll
      for (int j = 0; j < 16; ++j) f[j] = bp[(size_t)j * N];
      unsigned int pk[8];
      #pragma unroll
      for (int j = 0; j < 8; ++j)
        pk[j] = (unsigned int)f2bf(f[2*j]) | ((unsigned int)f2bf(f[2*j+1]) << 16);
      int sw = (bcol >> 1) & 3;
      int c0 = ((bhalf << 1)     ) ^ sw;
      int c1 = ((bhalf << 1) | 1 ) ^ sw;
      uint4 w0; w0.x = pk[0]; w0.y = pk[1]; w0.z = pk[2]; w0.w = pk[3];
      uint4 w1; w1.x = pk[4]; w1.y = pk[5]; w1.z = pk[6]; w1.w = pk[7];
      *(uint4*)(&Bs[bcol * 32 + c0 * 8]) = w0;
      *(uint4*)(&Bs[bcol * 32 + c1 * 8]) = w1;
    }
    __syncthreads();
    short8 a[4], b[4];
    #pragma unroll
    for (int m = 0; m < 4; ++m)
      a[m] = *(const short8*)(&As[(wr*64 + m*16 + l15) * 32 + g*8]);
    #pragma unroll
    for (int n = 0; n < 4; ++n){
      int col = wc*64 + n*16 + l15;
      b[n] = *(const short8*)(&Bs[col * 32 + (g ^ ((col >> 1) & 3)) * 8]);
    }
    #pragma unroll
    for (int m = 0; m < 4; ++m)
      #pragma unroll
      for (int n = 0; n < 4; ++n)
        acc[m][n] = __builtin_amdgcn_mfma_f32_16x16x32_bf16(a[m], b[n], acc[m][n], 0, 0, 0);
  }
  #pragma unroll
  for (int m = 0; m < 4; ++m)
    #pragma unroll
    for (int n = 0; n < 4; ++n){
      int row0 = m0 + wr*64 + m*16 + g*4;
      int col  = n0 + wc*64 + n*16 + l15;
      #pragma unroll
      for (int i = 0; i < 4; ++i)
        Cout[(size_t)(row0 + i) * N + col] = acc[m][n][i];
    }
}

// ---------------- flash attention: 4 waves/block, shared LDS K/V ----------------
__global__ __launch_bounds__(256) void attn_kernel(const unsigned short* __restrict__ q,
                                                   const unsigned short* __restrict__ k,
                                                   const unsigned short* __restrict__ vt,
                                                   unsigned short* __restrict__ ctx){
  const int tid = threadIdx.x;
  const int lane = tid & 63, w = tid >> 6;
  const int l15 = lane & 15, g = lane >> 4;
  const int q0 = blockIdx.x * 128 + w * 32;   // this wave's q base (seq-relative)
  const int hh = blockIdx.y;
  const int b  = blockIdx.z;
  const int tb = b * SEQ;

  __shared__ unsigned short Ks[64][72];       // [kv row][d]  padded
  __shared__ unsigned short Vs[64][72];       // [d][t]       padded
  __shared__ unsigned short Ps[4][2][16][72]; // per-wave P round-trip

  short8 qa[2][2];
  #pragma unroll
  for (int qs = 0; qs < 2; ++qs)
    #pragma unroll
    for (int kd = 0; kd < 2; ++kd)
      qa[qs][kd] = *(const short8*)(q + (size_t)(tb + q0 + qs*16 + l15) * HID + hh*HD + kd*32 + g*8);

  float m_run[2][4], l_run[2][4];
  f32x4 o_acc[2][4];
  #pragma unroll
  for (int qs = 0; qs < 2; ++qs)
    #pragma unroll
    for (int i = 0; i < 4; ++i){ m_run[qs][i] = -1e30f; l_run[qs][i] = 0.0f; }
  #pragma unroll
  for (int qs = 0; qs < 2; ++qs)
    #pragma unroll
    for (int dt = 0; dt < 4; ++dt)
      #pragma unroll
      for (int i = 0; i < 4; ++i) o_acc[qs][dt][i] = 0.0f;

  const int ntile = ((blockIdx.x * 128 + 127) >> 6) + 1;
  const int sr = tid >> 2, sc = (tid & 3) * 2;   // staging coords
  for (int kt = 0; kt < ntile; ++kt){
    const int kv0 = kt * 64;
    __syncthreads();
    *(uint4*)(&Ks[sr][sc*8])   = *(const uint4*)(k  + (size_t)(tb+kv0+sr)*HID + hh*HD + sc*8);
    *(uint4*)(&Ks[sr][sc*8+8]) = *(const uint4*)(k  + (size_t)(tb+kv0+sr)*HID + hh*HD + sc*8+8);
    *(uint4*)(&Vs[sr][sc*8])   = *(const uint4*)(vt + (size_t)(hh*HD+sr)*T_TOK + tb + kv0 + sc*8);
    *(uint4*)(&Vs[sr][sc*8+8]) = *(const uint4*)(vt + (size_t)(hh*HD+sr)*T_TOK + tb + kv0 + sc*8+8);
    __syncthreads();

    short8 kf[4][2];
    #pragma unroll
    for (int ct = 0; ct < 4; ++ct)
      #pragma unroll
      for (int kd = 0; kd < 2; ++kd)
        kf[ct][kd] = *(const short8*)(&Ks[ct*16 + l15][kd*32 + g*8]);

    #pragma unroll
    for (int qs = 0; qs < 2; ++qs){
      float pv[4][4];
      #pragma unroll
      for (int ct = 0; ct < 4; ++ct){
        f32x4 scv;
        #pragma unroll
        for (int i = 0; i < 4; ++i) scv[i] = 0.0f;
        scv = __builtin_amdgcn_mfma_f32_16x16x32_bf16(qa[qs][0], kf[ct][0], scv, 0, 0, 0);
        scv = __builtin_amdgcn_mfma_f32_16x16x32_bf16(qa[qs][1], kf[ct][1], scv, 0, 0, 0);
        #pragma unroll
        for (int i = 0; i < 4; ++i){
          float s = scv[i] * 0.125f;
          s = fminf(fmaxf(s, -1000.0f), 1000.0f);
          int row = q0 + qs*16 + g*4 + i;
          int col = kv0 + ct*16 + l15;
          pv[ct][i] = (col > row) ? -1e30f : s;
        }
      }
      #pragma unroll
      for (int i = 0; i < 4; ++i){
        float mx = fmaxf(fmaxf(pv[0][i], pv[1][i]), fmaxf(pv[2][i], pv[3][i]));
        #pragma unroll
        for (int msk = 1; msk < 16; msk <<= 1) mx = fmaxf(mx, __shfl_xor(mx, msk));
        float mnew = fmaxf(m_run[qs][i], mx);
        float scale = __expf(m_run[qs][i] - mnew);
        float psum = 0.0f;
        #pragma unroll
        for (int ct = 0; ct < 4; ++ct){
          float p = __expf(pv[ct][i] - mnew);
          pv[ct][i] = p; psum += p;
        }
        #pragma unroll
        for (int msk = 1; msk < 16; msk <<= 1) psum += __shfl_xor(psum, msk);
        l_run[qs][i] = l_run[qs][i] * scale + psum;
        m_run[qs][i] = mnew;
        #pragma unroll
        for (int dt = 0; dt < 4; ++dt) o_acc[qs][dt][i] *= scale;
      }
      #pragma unroll
      for (int ct = 0; ct < 4; ++ct)
        #pragma unroll
        for (int i = 0; i < 4; ++i)
          Ps[w][qs][g*4 + i][ct*16 + l15] = f2bf(pv[ct][i]);
    }
    #pragma unroll
    for (int ks = 0; ks < 2; ++ks){
      short8 vb[4];
      #pragma unroll
      for (int dt = 0; dt < 4; ++dt)
        vb[dt] = *(const short8*)(&Vs[dt*16 + l15][ks*32 + g*8]);
      #pragma unroll
      for (int qs = 0; qs < 2; ++qs){
        short8 ap = *(const short8*)(&Ps[w][qs][l15][ks*32 + g*8]);
        #pragma unroll
        for (int dt = 0; dt < 4; ++dt)
          o_acc[qs][dt] = __builtin_amdgcn_mfma_f32_16x16x32_bf16(ap, vb[dt], o_acc[qs][dt], 0, 0, 0);
      }
    }
  }
  #pragma unroll
  for (int qs = 0; qs < 2; ++qs)
    #pragma unroll
    for (int dt = 0; dt < 4; ++dt)
      #pragma unroll
      for (int i = 0; i < 4; ++i){
        float o = o_acc[qs][dt][i] / l_run[qs][i];
        ctx[(size_t)(tb + q0 + qs*16 + g*4 + i) * HID + hh*HD + dt*16 + l15] = f2bf(o);
      }
}

// ---------------- silu(g)*u -> g (bf16) ----------------
__global__ __launch_bounds__(256) void silu_mul_kernel(unsigned short* __restrict__ gbuf,
                                                       const unsigned short* __restrict__ ubuf){
  int i = blockIdx.x * 256 + threadIdx.x;
  ushort4 gv = ((const ushort4*)gbuf)[i];
  ushort4 uv = ((const ushort4*)ubuf)[i];
  ushort4 o;
  float x;
  x = bf2f(gv.x); o.x = f2bf((x / (1.0f + __expf(-x))) * bf2f(uv.x));
  x = bf2f(gv.y); o.y = f2bf((x / (1.0f + __expf(-x))) * bf2f(uv.y));
  x = bf2f(gv.z); o.z = f2bf((x / (1.0f + __expf(-x))) * bf2f(uv.z));
  x = bf2f(gv.w); o.w = f2bf((x / (1.0f + __expf(-x))) * bf2f(uv.w));
  ((ushort4*)gbuf)[i] = o;
}

extern "C" void kernel_launch(void* const* d_in, const int* in_sizes, int n_in,
                              void* d_out, int out_size, void* d_ws, size_t ws_size,
                              hipStream_t stream){
  const int*   ids    = (const int*)d_in[0];
  const float* embedW = (const float*)d_in[1];
  const float* Wq = (const float*)d_in[2];
  const float* Wk = (const float*)d_in[3];
  const float* Wv = (const float*)d_in[4];
  const float* Wo = (const float*)d_in[5];
  const float* Wg = (const float*)d_in[6];
  const float* Wu = (const float*)d_in[7];
  const float* Wd = (const float*)d_in[8];
  const float* n1 = (const float*)d_in[9];
  const float* n2 = (const float*)d_in[10];
  const float* nf = (const float*)d_in[11];
  const float* Wh = (const float*)d_in[12];
  float* out = (float*)d_out;

  // d_out scratch (dead until head GEMM, which reads only ws-resident xn/WhT)
  char* scb = (char*)d_out;
  unsigned short* qb  = (unsigned short*)(scb + 0);
  unsigned short* kb  = (unsigned short*)(scb + 8388608);
  unsigned short* vtb = (unsigned short*)(scb + 16777216);   // V^T [HID][T]
  unsigned short* ctx = (unsigned short*)(scb + 25165824);
  unsigned short* gb  = (unsigned short*)(scb + 33554432);
  unsigned short* ub  = (unsigned short*)(scb + 67108864);
  float* cosT = (float*)(scb + 100663296);
  float* sinT = (float*)(scb + 100925440);
  float* h_fallback   = (float*)(scb + 104857600);
  unsigned short* WtQ = (unsigned short*)(scb + 134217728);  // 16 MB
  unsigned short* WtK = (unsigned short*)(scb + 150994944);  // 16 MB
  unsigned short* WtV = (unsigned short*)(scb + 167772160);  // 16 MB
  unsigned short* WtO = (unsigned short*)(scb + 184549376);  // 16 MB
  unsigned short* WtG = (unsigned short*)(scb + 201326592);  // 64 MB
  unsigned short* WtU = (unsigned short*)(scb + 268435456);  // 64 MB
  unsigned short* WtD = (unsigned short*)(scb + 335544320);  // 64 MB -> ends 384 MB

  unsigned short* xn = (unsigned short*)d_ws;                // 8 MB (proven available)
  float* h = (ws_size >= 25165824u) ? (float*)((char*)d_ws + 8388608) : h_fallback;
  unsigned short* WhT = (ws_size >= 90701824u)
                      ? (unsigned short*)((char*)d_ws + 25165824) : nullptr;

  // weight pre-convert (bf16, transposed, swizzled)
  convert_w_kernel<<<dim3(16, 16, 8), 256, 0, stream>>>(Wq, WtQ, HID, HID);
  convert_w_kernel<<<dim3(16, 16, 8), 256, 0, stream>>>(Wk, WtK, HID, HID);
  convert_w_kernel<<<dim3(16, 16, 8), 256, 0, stream>>>(Wv, WtV, HID, HID);
  convert_w_kernel<<<dim3(16, 16, 8), 256, 0, stream>>>(Wo, WtO, HID, HID);
  convert_w_kernel<<<dim3(64, 16, 8), 256, 0, stream>>>(Wg, WtG, HID, INTER);
  convert_w_kernel<<<dim3(64, 16, 8), 256, 0, stream>>>(Wu, WtU, HID, INTER);
  convert_w_kernel<<<dim3(16, 64, 8), 256, 0, stream>>>(Wd, WtD, INTER, HID);
  if (WhT)
    convert_w_kernel<<<dim3(500, 16, 1), 256, 0, stream>>>(Wh, WhT, HID, VOCAB);

  embed_kernel<<<4096, 256, 0, stream>>>(ids, embedW, h);
  rope_tab_kernel<<<256, 256, 0, stream>>>(cosT, sinT);

  for (int l = 0; l < NLAYER; ++l){
    rmsnorm_kernel<<<4096, 256, 0, stream>>>(h, n1 + l*HID, xn, nullptr);
    gemm_qkv<<<dim3(32, 24), 256, 0, stream>>>(xn, WtQ + (size_t)l*HID*HID,
                                               WtK + (size_t)l*HID*HID,
                                               WtV + (size_t)l*HID*HID, qb, kb, vtb);
    rope_kernel<<<8192, 256, 0, stream>>>(qb, kb, cosT, sinT);
    attn_kernel<<<dim3(16, 16, 2), 256, 0, stream>>>(qb, kb, vtb, ctx);
    gemm_bf16<1><<<dim3(32, 8), 256, 0, stream>>>(ctx, WtO + (size_t)l*HID*HID,
                                                  h, h, HID, HID, 0);
    rmsnorm_kernel<<<4096, 256, 0, stream>>>(h, n2 + l*HID, xn, nullptr);
    gemm_gu<<<dim3(32, 64), 256, 0, stream>>>(xn, WtG + (size_t)l*HID*INTER,
                                              WtU + (size_t)l*HID*INTER, gb, ub);
    silu_mul_kernel<<<16384, 256, 0, stream>>>(gb, ub);
    gemm_bf16<1><<<dim3(32, 8), 256, 0, stream>>>(gb, WtD + (size_t)l*HID*INTER,
                                                  h, h, INTER, HID, 0);
  }

  rmsnorm_kernel<<<4096, 256, 0, stream>>>(h, nf, xn, out + 131072000);
  if (WhT)
    gemm_bf16<3><<<dim3(32, 250), 256, 0, stream>>>(xn, WhT, out, nullptr, HID, VOCAB, 0);
  else
    gemm_f32b<<<dim3(32, 250), 256, 0, stream>>>(xn, Wh, out, T_TOK, VOCAB, HID);
}